// Round 1
// 366.674 us; speedup vs baseline: 1.0971x; 1.0971x over previous
//
#include <hip/hip_runtime.h>
#include <math.h>

// Problem constants
#define NB   32768
#define AG   6
#define LL   225
#define DD   128
#define EE   5
#define NOUT 5
#define ADIM 64

// Workspace layout
#define WS_M        0        // floats: 128*128  M = q_w@k_w^T / 8
#define WS_W1T      16384    // floats: 5*128
#define WS_F2T      17024    // floats: 25*128
#define WS_BSWZ_B   80896    // bytes: B_swz = 8kb*8nt*3s*64lane*8 bf16 = 196608 B

// Encoder-as-MFMA tiling: block = 512 thr = 8 waves, 16 samples = 96 rows.
// M-tiles: 6 (16 rows). N-tiles: 8 (16 cols). Wave (wr,wc) = (w>>2, w&3)
// owns mt {3wr..3wr+2} x nt {2wc, 2wc+1}. K = 225 pad 256 = 8 K-steps of 32,
// staged in 4 chunks of 64.
#define SBLK 16
#define ENC_STRIDE 132       // enc LDS row stride (pad: 4*132 % 32 = 16 -> 2-way free)
#define LDS_FLOATS 12672     // max(A_swz 36864 B, enc 96*132*4 = 50688 B) = 50688 B

typedef __attribute__((ext_vector_type(8))) short short8v;
typedef __attribute__((ext_vector_type(4))) float float4v;

// bf16 RNE split helper (precompute/B-side only): bf16 bits of x, *rem exact
__device__ __forceinline__ unsigned short bf_hi(float x, float* rem) {
    unsigned u = __float_as_uint(x);
    unsigned r = (u + 0x7FFFu + ((u >> 16) & 1u)) & 0xFFFF0000u;
    *rem = x - __uint_as_float(r);
    return (unsigned short)(r >> 16);
}

// RZ (truncation) 3-level split of a float pair, packed bf16x2 words via v_perm.
// Exact residuals (Sterbenz); dropped terms in the 6-product scheme stay ~2^-23 rel.
struct Tri { unsigned h, m, l; };
__device__ __forceinline__ Tri split2(float x0, float x1) {
    Tri t;
    unsigned u0 = __float_as_uint(x0), u1 = __float_as_uint(x1);
    t.h = __builtin_amdgcn_perm(u1, u0, 0x07060302u);        // [hi16(x0), hi16(x1)]
    float r0 = x0 - __uint_as_float(u0 & 0xFFFF0000u);
    float r1 = x1 - __uint_as_float(u1 & 0xFFFF0000u);
    unsigned v0 = __float_as_uint(r0), v1 = __float_as_uint(r1);
    t.m = __builtin_amdgcn_perm(v1, v0, 0x07060302u);
    float q0 = r0 - __uint_as_float(v0 & 0xFFFF0000u);
    float q1 = r1 - __uint_as_float(v1 & 0xFFFF0000u);
    t.l = __builtin_amdgcn_perm(__float_as_uint(q1), __float_as_uint(q0), 0x07060302u);
    return t;
}

// Stage one 8-element k-group of one obs row into A_swz, b128 writes, pi-swizzled.
// A_swz slab = [kbL][mt][s]: 64 blocks of 8 ushorts; block index pi(la)=la^((la>>2)&12).
__device__ __forceinline__ void stage8(unsigned short* aswz, const float* obs_blk,
                                       int slot, int k0) {
    const int r  = slot >> 3;        // row 0..95
    const int k8 = slot & 7;         // which 8-wide k group in the 64-chunk
    const int k  = k0 + 8 * k8;
    float4 v0 = make_float4(0.f, 0.f, 0.f, 0.f);
    float4 v1 = make_float4(0.f, 0.f, 0.f, 0.f);
    if (k + 7 <= 224) {
        v0 = *(const float4*)&obs_blk[r * LL + k];
        v1 = *(const float4*)&obs_blk[r * LL + k + 4];
    } else if (k == 224) {
        v0.x = obs_blk[r * LL + 224];
    }
    Tri a = split2(v0.x, v0.y);
    Tri b = split2(v0.z, v0.w);
    Tri cc = split2(v1.x, v1.y);
    Tri d = split2(v1.z, v1.w);
    const int mt  = r >> 4, mm = r & 15;
    const int kbL = k8 >> 2;
    const int la  = mm + 16 * (k8 & 3);          // frag lane: A[row=la&15][k=(la>>4)*8+j]
    const int pla = la ^ ((la >> 2) & 12);       // bank-spread permutation
    unsigned short* p = aswz + ((kbL * 6 + mt) * 3) * 512 + pla * 8;
    *(uint4*)(p)        = make_uint4(a.h, b.h, cc.h, d.h);
    *(uint4*)(p + 512)  = make_uint4(a.m, b.m, cc.m, d.m);
    *(uint4*)(p + 1024) = make_uint4(a.l, b.l, cc.l, d.l);
}

__global__ void precompute_kernel(const float* __restrict__ q_w,
                                  const float* __restrict__ k_w,
                                  const float* __restrict__ enc_w,
                                  const float* __restrict__ fc_w,
                                  float* __restrict__ ws) {
    int b = blockIdx.x;
    int t = threadIdx.x;
    if (b < 128) {
        float s = 0.f;
        #pragma unroll 8
        for (int j = 0; j < ADIM; ++j)
            s = fmaf(q_w[b * ADIM + j], k_w[t * ADIM + j], s);
        ws[WS_M + b * 128 + t] = s * 0.125f;
    } else if (b == 128) {
        int d = t;
        #pragma unroll
        for (int o = 0; o < NOUT; ++o) {
            float s = 0.f;
            #pragma unroll
            for (int e = 0; e < EE; ++e)
                s += fc_w[(e * 128 + d) * NOUT + o];
            ws[WS_W1T + o * 128 + d] = s;
            #pragma unroll
            for (int e = 0; e < EE; ++e)
                ws[WS_F2T + (e * 5 + o) * 128 + d] = fc_w[(640 + e * 128 + d) * NOUT + o];
        }
    } else {
        // B_swz: enc_w -> bf16x3, MFMA B-frag order.
        // B-frag (16x16x32): lane holds B[k = (lane>>4)*8 + j][n = lane&15], j=0..7
        int idx = (b - 129) * 128 + t;          // 0..12287 = kb*8nt*3s*64lane
        int lane = idx & 63;
        int rest = idx >> 6;                    // 0..191
        int s    = rest % 3;
        int r2   = rest / 3;                    // 0..63
        int nt   = r2 & 7;
        int kb   = r2 >> 3;
        unsigned short* bs = (unsigned short*)((char*)ws + WS_BSWZ_B);
        const int n     = nt * 16 + (lane & 15);
        const int kbase = kb * 32 + (lane >> 4) * 8;
        #pragma unroll
        for (int j = 0; j < 8; ++j) {
            int k = kbase + j;
            float x = (k < LL) ? enc_w[k * DD + n] : 0.f;
            float q1, q2, q3;
            unsigned short h = bf_hi(x,  &q1);
            unsigned short m = bf_hi(q1, &q2);
            unsigned short l = bf_hi(q2, &q3);
            bs[(((kb * 8 + nt) * 3 + s) * 64 + lane) * 8 + j] =
                (s == 0) ? h : (s == 1) ? m : l;
        }
    }
}

__global__ __launch_bounds__(512, 4)
void policy_kernel(const float* __restrict__ obs,
                   const float* __restrict__ enc_b,
                   const float* __restrict__ fc_b,
                   const float* __restrict__ u,
                   const float* __restrict__ ws,
                   int* __restrict__ out) {
    __shared__ float lds[LDS_FLOATS];
    unsigned short* aswz = (unsigned short*)lds;

    const int tid  = threadIdx.x;
    const int lane = tid & 63;
    const int w    = tid >> 6;           // 0..7
    const int wr   = w >> 2;             // 0..1  (mt group)
    const int wc   = w & 3;              // 0..3  (nt group)
    const int bs0  = blockIdx.x * SBLK;
    const float* obs_blk = obs + (size_t)bs0 * (AG * LL);
    const unsigned short* bswz = (const unsigned short*)((const char*)ws + WS_BSWZ_B);
    const int pl8 = (lane ^ ((lane >> 2) & 12)) * 8;   // swizzled A-frag read offset

    // ---- encoder: C[96][128] = obs[96][256pad] @ enc_w[256pad][128], bf16x3 ----
    float4v acc[3][2];
    #pragma unroll
    for (int m3 = 0; m3 < 3; ++m3)
        #pragma unroll
        for (int nt = 0; nt < 2; ++nt)
            acc[m3][nt] = (float4v){0.f, 0.f, 0.f, 0.f};

    #pragma unroll 1
    for (int c = 0; c < 4; ++c) {
        const int k0 = 64 * c;
        // ---- stage A chunk: 96 rows x 64 k = 768 slots of 8 elems ----
        stage8(aswz, obs_blk, tid, k0);
        if (tid < 256) stage8(aswz, obs_blk, 512 + tid, k0);
        __syncthreads();

        // ---- MFMA over the 2 K-steps of this chunk ----
        #pragma unroll
        for (int kbL = 0; kbL < 2; ++kbL) {
            const int kb = 2 * c + kbL;
            short8v Bf[2][3];
            #pragma unroll
            for (int nt = 0; nt < 2; ++nt)
                #pragma unroll
                for (int s = 0; s < 3; ++s)
                    Bf[nt][s] = *(const short8v*)
                        &bswz[(((kb * 8 + (2 * wc + nt)) * 3 + s) * 64 + lane) * 8];
            #pragma unroll
            for (int m3 = 0; m3 < 3; ++m3) {
                const unsigned short* ap =
                    aswz + ((kbL * 6 + (wr * 3 + m3)) * 3) * 512 + pl8;
                short8v Ah = *(const short8v*)(ap);
                short8v Am = *(const short8v*)(ap + 512);
                short8v Al = *(const short8v*)(ap + 1024);
                #pragma unroll
                for (int nt = 0; nt < 2; ++nt) {
                    float4v d = acc[m3][nt];
                    d = __builtin_amdgcn_mfma_f32_16x16x32_bf16(Ah, Bf[nt][0], d, 0, 0, 0);
                    d = __builtin_amdgcn_mfma_f32_16x16x32_bf16(Ah, Bf[nt][1], d, 0, 0, 0);
                    d = __builtin_amdgcn_mfma_f32_16x16x32_bf16(Am, Bf[nt][0], d, 0, 0, 0);
                    d = __builtin_amdgcn_mfma_f32_16x16x32_bf16(Ah, Bf[nt][2], d, 0, 0, 0);
                    d = __builtin_amdgcn_mfma_f32_16x16x32_bf16(Al, Bf[nt][0], d, 0, 0, 0);
                    d = __builtin_amdgcn_mfma_f32_16x16x32_bf16(Am, Bf[nt][1], d, 0, 0, 0);
                    acc[m3][nt] = d;
                }
            }
        }
        __syncthreads();   // A_swz dead before next chunk's staging (or enc write)
    }

    // ---- unload C tiles -> enc LDS [96][132] with bias+relu ----
    // C/D layout (verified m89): col = lane&15, row = (lane>>4)*4 + reg
    {
        #pragma unroll
        for (int nt = 0; nt < 2; ++nt) {
            const int col = (2 * wc + nt) * 16 + (lane & 15);
            const float bb = enc_b[col];
            #pragma unroll
            for (int m3 = 0; m3 < 3; ++m3) {
                const int rbase = (wr * 3 + m3) * 16 + (lane >> 4) * 4;
                #pragma unroll
                for (int reg = 0; reg < 4; ++reg)
                    lds[(rbase + reg) * ENC_STRIDE + col] =
                        fmaxf(acc[m3][nt][reg] + bb, 0.f);
            }
        }
    }
    __syncthreads();

    // ---- phase 2: wave w owns samples 2w, 2w+1 ----
    const float* Mw = ws + WS_M;
    const int c0 = 2 * lane;
    const int sA = 2 * w;                // block-local samples sA, sA+1
    const int rA = sA * AG;              // enc row of agent 0
    const int rB = rA + AG;

    // t = ag_e @ M for both samples
    float t0[2] = {0.f, 0.f}, t1[2] = {0.f, 0.f};
    #pragma unroll 4
    for (int d = 0; d < DD; d += 4) {
        float4 a0 = *(const float4*)&lds[rA * ENC_STRIDE + d];
        float4 a1 = *(const float4*)&lds[rB * ENC_STRIDE + d];
        float2 m0 = *(const float2*)&Mw[(size_t)(d + 0) * DD + c0];
        float2 m1 = *(const float2*)&Mw[(size_t)(d + 1) * DD + c0];
        float2 m2 = *(const float2*)&Mw[(size_t)(d + 2) * DD + c0];
        float2 m3 = *(const float2*)&Mw[(size_t)(d + 3) * DD + c0];
        t0[0] = fmaf(a0.x, m0.x, t0[0]); t1[0] = fmaf(a0.x, m0.y, t1[0]);
        t0[0] = fmaf(a0.y, m1.x, t0[0]); t1[0] = fmaf(a0.y, m1.y, t1[0]);
        t0[0] = fmaf(a0.z, m2.x, t0[0]); t1[0] = fmaf(a0.z, m2.y, t1[0]);
        t0[0] = fmaf(a0.w, m3.x, t0[0]); t1[0] = fmaf(a0.w, m3.y, t1[0]);
        t0[1] = fmaf(a1.x, m0.x, t0[1]); t1[1] = fmaf(a1.x, m0.y, t1[1]);
        t0[1] = fmaf(a1.y, m1.x, t0[1]); t1[1] = fmaf(a1.y, m1.y, t1[1]);
        t0[1] = fmaf(a1.z, m2.x, t0[1]); t1[1] = fmaf(a1.z, m2.y, t1[1]);
        t0[1] = fmaf(a1.w, m3.x, t0[1]); t1[1] = fmaf(a1.w, m3.y, t1[1]);
    }

    // scores (partial over this lane's col pair), then butterfly
    float vx[2][EE], vy[2][EE], sc[2][EE];
    #pragma unroll
    for (int j = 0; j < 2; ++j)
        #pragma unroll
        for (int e = 0; e < EE; ++e) {
            float2 v = *(const float2*)&lds[((sA + j) * AG + 1 + e) * ENC_STRIDE + c0];
            vx[j][e] = v.x; vy[j][e] = v.y;
            sc[j][e] = t0[j] * v.x + t1[j] * v.y;
        }
    #pragma unroll
    for (int off = 32; off > 0; off >>= 1)
        #pragma unroll
        for (int j = 0; j < 2; ++j)
            #pragma unroll
            for (int e = 0; e < EE; ++e)
                sc[j][e] += __shfl_xor(sc[j][e], off, 64);

    float alpha[2][EE];
    #pragma unroll
    for (int j = 0; j < 2; ++j) {
        float mx = sc[j][0];
        #pragma unroll
        for (int e = 1; e < EE; ++e) mx = fmaxf(mx, sc[j][e]);
        float sum = 0.f;
        #pragma unroll
        for (int e = 0; e < EE; ++e) { alpha[j][e] = expf(sc[j][e] - mx); sum += alpha[j][e]; }
        const float inv = 1.f / sum;
        #pragma unroll
        for (int e = 0; e < EE; ++e) alpha[j][e] *= inv;
    }

    // logits (partial over col pair), butterfly
    float Lg[2][NOUT];
    #pragma unroll
    for (int j = 0; j < 2; ++j) {
        float2 a2 = *(const float2*)&lds[(sA + j) * AG * ENC_STRIDE + c0];
        #pragma unroll
        for (int o = 0; o < NOUT; ++o) {
            float2 w1 = *(const float2*)&ws[WS_W1T + o * DD + c0];
            Lg[j][o] = fmaf(a2.x, w1.x, a2.y * w1.y);
        }
    }
    #pragma unroll
    for (int e = 0; e < EE; ++e) {
        float wxj[2], wyj[2];
        #pragma unroll
        for (int j = 0; j < 2; ++j) { wxj[j] = alpha[j][e] * vx[j][e]; wyj[j] = alpha[j][e] * vy[j][e]; }
        #pragma unroll
        for (int o = 0; o < NOUT; ++o) {
            float2 f2 = *(const float2*)&ws[WS_F2T + (e * NOUT + o) * DD + c0];
            #pragma unroll
            for (int j = 0; j < 2; ++j)
                Lg[j][o] = fmaf(wxj[j], f2.x, fmaf(wyj[j], f2.y, Lg[j][o]));
        }
    }
    #pragma unroll
    for (int off = 32; off > 0; off >>= 1)
        #pragma unroll
        for (int j = 0; j < 2; ++j)
            #pragma unroll
            for (int o = 0; o < NOUT; ++o)
                Lg[j][o] += __shfl_xor(Lg[j][o], off, 64);

    // Gumbel + argmax (monotone -> skip softmax/tau)
    const int S0 = bs0 + sA;
    float y = -1e30f;
    if (lane < 10) {
        const int jl = lane / 5, ol = lane - 5 * jl;
        const float uu  = u[(size_t)S0 * NOUT + lane];
        const float gmb = -logf(-logf(uu + 1e-10f) + 1e-10f);
        y = Lg[jl][ol] + fc_b[ol] + gmb;
    }
    float b0 = -1e30f, b1 = -1e30f; int bi0 = 0, bi1 = 0;
    #pragma unroll
    for (int o = 0; o < NOUT; ++o) {
        float y0 = __shfl(y, o, 64);
        float y1 = __shfl(y, 5 + o, 64);
        if (y0 > b0) { b0 = y0; bi0 = o; }   // strict > == np.argmax first-max
        if (y1 > b1) { b1 = y1; bi1 = o; }
    }
    if (lane < 2) out[S0 + lane] = lane ? bi1 : bi0;
}

extern "C" void kernel_launch(void* const* d_in, const int* in_sizes, int n_in,
                              void* d_out, int out_size, void* d_ws, size_t ws_size,
                              hipStream_t stream) {
    const float* obs   = (const float*)d_in[0];
    const float* enc_w = (const float*)d_in[1];
    const float* enc_b = (const float*)d_in[2];
    const float* q_w   = (const float*)d_in[3];
    const float* k_w   = (const float*)d_in[4];
    const float* fc_w  = (const float*)d_in[5];
    const float* fc_b  = (const float*)d_in[6];
    const float* uu    = (const float*)d_in[7];
    float* ws = (float*)d_ws;
    int*   po = (int*)d_out;

    precompute_kernel<<<225, 128, 0, stream>>>(q_w, k_w, enc_w, fc_w, ws);
    policy_kernel<<<NB / SBLK, 512, 0, stream>>>(obs, enc_b, fc_b, uu, ws, po);
}